// Round 1
// baseline (753.804 us; speedup 1.0000x reference)
//
#include <hip/hip_runtime.h>

#define IN_CH 16
#define OUT_CH 16
#define EDGE_FEAT 32
#define HIDDEN 128
#define WROW 256          // IN_CH*OUT_CH
#define FPB 8             // filters per block in filter-net kernel
#define EPT 8             // edges per thread in edge kernel

// ---------------- Kernel 1: filter net -------------------------------------
// weights[f][i*16+o] = (relu(ef[f]@W1 + b1) @ W2 + b2)[i*16+o]
// 8 filters per 256-thread block; W2 row loaded once, reused for all 8.
__global__ __launch_bounds__(256) void filter_net_kernel(
    const float* __restrict__ ef, const float* __restrict__ W1,
    const float* __restrict__ b1, const float* __restrict__ W2,
    const float* __restrict__ b2, float* __restrict__ weights) {
  __shared__ float ef_s[FPB * EDGE_FEAT];   // 256 floats
  __shared__ float h_s[FPB][HIDDEN];        // 1024 floats
  const int t = threadIdx.x;
  const int f0 = blockIdx.x * FPB;

  // stage 0: 8 consecutive edgefeat rows = 256 contiguous floats
  ef_s[t] = ef[f0 * EDGE_FEAT + t];
  __syncthreads();

  // stage 1: hidden layer. 8*128 = 1024 h-values, 4 per thread.
  #pragma unroll
  for (int j = 0; j < (FPB * HIDDEN) / 256; ++j) {
    const int idx = t + j * 256;
    const int fi = idx >> 7;        // /HIDDEN
    const int hi = idx & (HIDDEN - 1);
    float a = b1[hi];
    #pragma unroll
    for (int k = 0; k < EDGE_FEAT; ++k)
      a = fmaf(ef_s[fi * EDGE_FEAT + k], W1[k * HIDDEN + hi], a);
    h_s[fi][hi] = a > 0.f ? a : 0.f;
  }
  __syncthreads();

  // stage 2: output layer. thread t owns column t for all 8 filters.
  float acc[FPB];
  const float bb = b2[t];
  #pragma unroll
  for (int fi = 0; fi < FPB; ++fi) acc[fi] = bb;
  for (int k = 0; k < HIDDEN; ++k) {
    const float w2 = W2[k * WROW + t];       // coalesced, reused x8
    #pragma unroll
    for (int fi = 0; fi < FPB; ++fi)
      acc[fi] = fmaf(h_s[fi][k], w2, acc[fi]);
  }
  #pragma unroll
  for (int fi = 0; fi < FPB; ++fi)
    weights[(size_t)(f0 + fi) * WROW + t] = acc[fi];
}

// ---------------- Kernel 2: per-edge bmm + segmented atomic reduce ----------
__device__ __forceinline__ void flush_seg(float* __restrict__ sums,
                                          float* __restrict__ deg,
                                          int s, const float4* acc4, float cnt) {
  if (cnt <= 0.f) return;
  float* p = sums + (size_t)s * OUT_CH;
  const float* a = (const float*)acc4;
  #pragma unroll
  for (int c = 0; c < OUT_CH; ++c) atomicAdd(p + c, a[c]);
  atomicAdd(deg + s, cnt);
}

__global__ __launch_bounds__(256) void edge_kernel(
    const float* __restrict__ input, const int* __restrict__ idxn,
    const int* __restrict__ idxe, const int* __restrict__ seg,
    const float* __restrict__ weights, float* __restrict__ sums,
    float* __restrict__ deg, int n_edges) {
  const long base = (long)(blockIdx.x * blockDim.x + threadIdx.x) * EPT;
  float4 acc4[4];
  #pragma unroll
  for (int j = 0; j < 4; ++j) acc4[j] = make_float4(0.f, 0.f, 0.f, 0.f);
  int cur = -1;
  float cnt = 0.f;

  for (int q = 0; q < EPT; ++q) {
    const long e = base + q;
    if (e >= n_edges) break;
    const int s = seg[e];
    if (s != cur) {
      flush_seg(sums, deg, cur, acc4, cnt);
      cur = s;
      cnt = 0.f;
      #pragma unroll
      for (int j = 0; j < 4; ++j) acc4[j] = make_float4(0.f, 0.f, 0.f, 0.f);
    }
    const int n = idxn[e];
    const int f = idxe[e];
    const float4* __restrict__ xp =
        (const float4*)(input + (size_t)n * IN_CH);
    float x[IN_CH];
    *(float4*)&x[0]  = xp[0];
    *(float4*)&x[4]  = xp[1];
    *(float4*)&x[8]  = xp[2];
    *(float4*)&x[12] = xp[3];
    const float4* __restrict__ wp =
        (const float4*)(weights + (size_t)f * WROW);
    #pragma unroll
    for (int i = 0; i < IN_CH; ++i) {
      const float xi = x[i];
      #pragma unroll
      for (int j = 0; j < 4; ++j) {
        const float4 w4 = wp[i * 4 + j];
        acc4[j].x = fmaf(xi, w4.x, acc4[j].x);
        acc4[j].y = fmaf(xi, w4.y, acc4[j].y);
        acc4[j].z = fmaf(xi, w4.z, acc4[j].z);
        acc4[j].w = fmaf(xi, w4.w, acc4[j].w);
      }
    }
    cnt += 1.f;
  }
  flush_seg(sums, deg, cur, acc4, cnt);
}

// ---------------- Kernel 3: divide by degree --------------------------------
__global__ __launch_bounds__(256) void finalize_kernel(
    const float* __restrict__ sums, const float* __restrict__ deg,
    float* __restrict__ out, int n_nodes) {
  const int n = blockIdx.x * blockDim.x + threadIdx.x;
  if (n >= n_nodes) return;
  const float d = deg[n];
  const float scale = d > 0.f ? 1.f / d : 0.f;
  const float4* sp = (const float4*)(sums + (size_t)n * OUT_CH);
  float4* op = (float4*)(out + (size_t)n * OUT_CH);
  #pragma unroll
  for (int j = 0; j < 4; ++j) {
    float4 v = sp[j];
    v.x *= scale; v.y *= scale; v.z *= scale; v.w *= scale;
    op[j] = v;
  }
}

extern "C" void kernel_launch(void* const* d_in, const int* in_sizes, int n_in,
                              void* d_out, int out_size, void* d_ws, size_t ws_size,
                              hipStream_t stream) {
  const float* input = (const float*)d_in[0];
  const int* idxn    = (const int*)d_in[1];
  const int* idxe    = (const int*)d_in[2];
  const int* seg     = (const int*)d_in[3];
  const float* ef    = (const float*)d_in[4];
  const float* W1    = (const float*)d_in[5];
  const float* b1    = (const float*)d_in[6];
  const float* W2    = (const float*)d_in[7];
  const float* b2    = (const float*)d_in[8];
  float* out = (float*)d_out;

  const int n_nodes   = in_sizes[0] / IN_CH;
  const int n_edges   = in_sizes[1];
  const int n_filters = in_sizes[4] / EDGE_FEAT;

  // workspace layout: weights[F*256] | sums[n_nodes*16] | deg[n_nodes]
  float* weights = (float*)d_ws;
  float* sums    = weights + (size_t)n_filters * WROW;
  float* deg     = sums + (size_t)n_nodes * OUT_CH;

  hipMemsetAsync(sums, 0,
                 (size_t)(n_nodes * OUT_CH + n_nodes) * sizeof(float), stream);

  filter_net_kernel<<<n_filters / FPB, 256, 0, stream>>>(ef, W1, b1, W2, b2,
                                                         weights);

  const int n_threads = (n_edges + EPT - 1) / EPT;
  edge_kernel<<<(n_threads + 255) / 256, 256, 0, stream>>>(
      input, idxn, idxe, seg, weights, sums, deg, n_edges);

  finalize_kernel<<<(n_nodes + 255) / 256, 256, 0, stream>>>(sums, deg, out,
                                                             n_nodes);
}